// Round 17
// baseline (135.681 us; speedup 1.0000x reference)
//
#include <hip/hip_runtime.h>
#include <math.h>

namespace {

constexpr int NC  = 64;      // coarse samples
constexpr int NF  = 128;     // fine (importance) samples
constexpr int NT  = NC + NF; // 192 total fine-pass samples
constexpr int HID = 128;
constexpr float T_NEAR = 2.0f, T_FAR = 6.0f;
constexpr int RPB = 8;       // rays per block: grid=1024 -> 4 blk/CU -> 1 wave/SIMD

typedef __attribute__((ext_vector_type(8)))  short bf16x8;   // 8 bf16 = 4 VGPRs
typedef __attribute__((ext_vector_type(16))) float f32x16;   // MFMA 32x32 acc
typedef __attribute__((ext_vector_type(4)))  unsigned int u32x4;
typedef __attribute__((ext_vector_type(2)))  __bf16 vbf2;

__device__ __forceinline__ unsigned int pk2(float a, float b) {
  vbf2 t; t[0] = (__bf16)a; t[1] = (__bf16)b;   // v_cvt_pk_bf16_f32
  return __builtin_bit_cast(unsigned int, t);
}
__device__ __forceinline__ bf16x8 mk4(unsigned int w0, unsigned int w1,
                                      unsigned int w2, unsigned int w3) {
  u32x4 u = {w0, w1, w2, w3};
  return __builtin_bit_cast(bf16x8, u);
}
__device__ __forceinline__ f32x16 zero16() {
  f32x16 z;
  #pragma unroll
  for (int i = 0; i < 16; ++i) z[i] = 0.f;
  return z;
}
__device__ __forceinline__ f32x16 mfma(bf16x8 a, bf16x8 b, f32x16 c) {
  return __builtin_amdgcn_mfma_f32_32x32x16_bf16(a, b, c, 0, 0, 0);
}

// ---------- DPP wave scans (pure VALU) ----------
template<int CTRL, int RMASK>
__device__ __forceinline__ float dpp_fmul(float x) {
  int sh = __builtin_amdgcn_update_dpp(0x3f800000 /*1.0f*/,
                                       __builtin_bit_cast(int, x),
                                       CTRL, RMASK, 0xf, false);
  return x * __builtin_bit_cast(float, sh);
}
template<int CTRL, int RMASK>
__device__ __forceinline__ float dpp_fadd(float x) {
  int sh = __builtin_amdgcn_update_dpp(0 /*0.0f*/,
                                       __builtin_bit_cast(int, x),
                                       CTRL, RMASK, 0xf, false);
  return x + __builtin_bit_cast(float, sh);
}
template<int CTRL, int RMASK>
__device__ __forceinline__ int dpp_iadd(int x) {
  return x + __builtin_amdgcn_update_dpp(0, x, CTRL, RMASK, 0xf, false);
}
__device__ __forceinline__ float dpp_scan_mul(float x) {
  x = dpp_fmul<0x111, 0xf>(x);
  x = dpp_fmul<0x112, 0xf>(x);
  x = dpp_fmul<0x114, 0xf>(x);
  x = dpp_fmul<0x118, 0xf>(x);
  x = dpp_fmul<0x142, 0xa>(x);
  x = dpp_fmul<0x143, 0xc>(x);
  return x;
}
__device__ __forceinline__ float dpp_scan_add(float x) {
  x = dpp_fadd<0x111, 0xf>(x);
  x = dpp_fadd<0x112, 0xf>(x);
  x = dpp_fadd<0x114, 0xf>(x);
  x = dpp_fadd<0x118, 0xf>(x);
  x = dpp_fadd<0x142, 0xa>(x);
  x = dpp_fadd<0x143, 0xc>(x);
  return x;
}
__device__ __forceinline__ int dpp_scan_addi(int x) {
  x = dpp_iadd<0x111, 0xf>(x);
  x = dpp_iadd<0x112, 0xf>(x);
  x = dpp_iadd<0x114, 0xf>(x);
  x = dpp_iadd<0x118, 0xf>(x);
  x = dpp_iadd<0x142, 0xa>(x);
  x = dpp_iadd<0x143, 0xc>(x);
  return x;
}

// k-slot permutation (HW-verified round 4): slot (k9,hi,i) of the B operand
// holds, in-lane, C-tile register r of the producing layer.
__device__ __forceinline__ int kperm(int k9, int hi, int i) {
  return 32 * (k9 >> 1) + 16 * (k9 & 1) + 4 * hi + (i & 3) + 8 * (i >> 2);
}

// acc C-tile -> relu -> two B-fragment ksteps, pure in-lane VALU.
__device__ __forceinline__ void cvt_direct(const f32x16& a, bf16x8& bE, bf16x8& bO) {
  float v[16];
  #pragma unroll
  for (int r = 0; r < 16; ++r) v[r] = fmaxf(a[r], 0.f);
  bE = mk4(pk2(v[0],  v[1]),  pk2(v[2],  v[3]),
           pk2(v[4],  v[5]),  pk2(v[6],  v[7]));
  bO = mk4(pk2(v[8],  v[9]),  pk2(v[10], v[11]),
           pk2(v[12], v[13]), pk2(v[14], v[15]));
}

struct Wfrag {           // ALL weights resident in registers (~200 VGPRs)
  bf16x8 a1[4];          // W1ext^T [hid][k: x,y,z,b1]
  bf16x8 a2[4][9];       // W2ext^T, k<128 pi-permuted; k9=8: k=128 -> b2
  bf16x8 ah[9];          // head^T, k<128 pi-permuted; k9=8: dirs+bias
  bf16x8 bOne;           // B kstep8 of layer2: slot 128 -> 1.0
};

__device__ __forceinline__ void load_weights(Wfrag& w, int lane,
    const float* __restrict__ W1,  const float* __restrict__ b1,
    const float* __restrict__ W2,  const float* __restrict__ b2,
    const float* __restrict__ Wsg, const float* __restrict__ bsg,
    const float* __restrict__ Wrg, const float* __restrict__ brg) {
  const int hl = lane & 31;
  const int hi = lane >> 5;
  const bool lo = (lane < 32);

  #pragma unroll
  for (int m = 0; m < 4; ++m) {
    int h = 32 * m + hl;
    w.a1[m] = lo ? mk4(pk2(W1[h], W1[HID + h]), pk2(W1[2 * HID + h], b1[h]), 0u, 0u)
                 : mk4(0u, 0u, 0u, 0u);
  }
  #pragma unroll
  for (int m = 0; m < 4; ++m) {
    int h = 32 * m + hl;
    #pragma unroll
    for (int k9 = 0; k9 < 9; ++k9) {
      float e[8];
      #pragma unroll
      for (int i = 0; i < 8; ++i) {
        if (k9 < 8) e[i] = W2[kperm(k9, hi, i) * HID + h];
        else        e[i] = (8 * hi + i == 0) ? b2[h] : 0.f;
      }
      w.a2[m][k9] = mk4(pk2(e[0], e[1]), pk2(e[2], e[3]),
                        pk2(e[4], e[5]), pk2(e[6], e[7]));
    }
  }
  const int c = hl;
  #pragma unroll
  for (int k9 = 0; k9 < 9; ++k9) {
    float e[8];
    #pragma unroll
    for (int i = 0; i < 8; ++i) {
      int kk = (k9 < 8) ? kperm(k9, hi, i) : (128 + 8 * hi + i);
      float v = 0.f;
      if (c == 0)       { if (kk < 128) v = Wsg[kk]; else if (kk == 131) v = bsg[0]; }
      else if (c <= 3)  { if (kk < 131) v = Wrg[kk * 3 + (c - 1)]; else if (kk == 131) v = brg[c - 1]; }
      e[i] = v;
    }
    w.ah[k9] = mk4(pk2(e[0], e[1]), pk2(e[2], e[3]),
                   pk2(e[4], e[5]), pk2(e[6], e[7]));
  }
  w.bOne = lo ? mk4(pk2(1.f, 0.f), 0u, 0u, 0u) : mk4(0u, 0u, 0u, 0u);
}

__device__ __forceinline__ float sigm(float x) { return 1.f / (1.f + __expf(-x)); }

// N independent 32-sample tiles, acc-major schedule (round-14 verified):
// all 4 layer-2 accumulators live; each L1 cvt feeds 8 independent MFMAs.
// Per-accumulator summation order identical to rounds 4-16 (bitwise).
template<int N>
__device__ __forceinline__ void mlp_tileN(const Wfrag& w, const float* ts,
    float ox, float oy, float oz, float dxx, float dyy, float dzz,
    bf16x8 dirB, int lane, float4* outT) {
  const bool lo = (lane < 32);

  bf16x8 bP[N];
  #pragma unroll
  for (int n = 0; n < N; ++n) {
    float px = fmaf(dxx, ts[n], ox), py = fmaf(dyy, ts[n], oy), pz = fmaf(dzz, ts[n], oz);
    bP[n] = lo ? mk4(pk2(px, py), pk2(pz, 1.f), 0u, 0u) : mk4(0u, 0u, 0u, 0u);
  }

  f32x16 acc0[N], acc1[N], acc2[N], acc3[N];   // named: static allocation
  f32x16 hacc[N];
  #pragma unroll
  for (int n = 0; n < N; ++n) {
    acc0[n] = zero16(); acc1[n] = zero16();
    acc2[n] = zero16(); acc3[n] = zero16();
    hacc[n] = zero16();
  }

  // layer 1 (4 MFMA + 4 cvt per tile) feeding all 4 layer-2 acc chains
  #pragma unroll
  for (int m1 = 0; m1 < 4; ++m1) {
    #pragma unroll
    for (int n = 0; n < N; ++n) {
      f32x16 l1 = mfma(w.a1[m1], bP[n], zero16());
      bf16x8 hE, hO;
      cvt_direct(l1, hE, hO);                  // bH ksteps {2m1, 2m1+1}
      acc0[n] = mfma(w.a2[0][2 * m1], hE, acc0[n]);
      acc0[n] = mfma(w.a2[0][2 * m1 + 1], hO, acc0[n]);
      acc1[n] = mfma(w.a2[1][2 * m1], hE, acc1[n]);
      acc1[n] = mfma(w.a2[1][2 * m1 + 1], hO, acc1[n]);
      acc2[n] = mfma(w.a2[2][2 * m1], hE, acc2[n]);
      acc2[n] = mfma(w.a2[2][2 * m1 + 1], hO, acc2[n]);
      acc3[n] = mfma(w.a2[3][2 * m1], hE, acc3[n]);
      acc3[n] = mfma(w.a2[3][2 * m1 + 1], hO, acc3[n]);
    }
  }
  // b2 bias kstep (same position in per-acc order as before)
  #pragma unroll
  for (int n = 0; n < N; ++n) {
    acc0[n] = mfma(w.a2[0][8], w.bOne, acc0[n]);
    acc1[n] = mfma(w.a2[1][8], w.bOne, acc1[n]);
    acc2[n] = mfma(w.a2[2][8], w.bOne, acc2[n]);
    acc3[n] = mfma(w.a2[3][8], w.bOne, acc3[n]);
  }
  // head: 4 cvt + 9 MFMA per tile
  #pragma unroll
  for (int n = 0; n < N; ++n) {
    bf16x8 bE, bO;
    cvt_direct(acc0[n], bE, bO);
    hacc[n] = mfma(w.ah[0], bE, hacc[n]);
    hacc[n] = mfma(w.ah[1], bO, hacc[n]);
    cvt_direct(acc1[n], bE, bO);
    hacc[n] = mfma(w.ah[2], bE, hacc[n]);
    hacc[n] = mfma(w.ah[3], bO, hacc[n]);
    cvt_direct(acc2[n], bE, bO);
    hacc[n] = mfma(w.ah[4], bE, hacc[n]);
    hacc[n] = mfma(w.ah[5], bO, hacc[n]);
    cvt_direct(acc3[n], bE, bO);
    hacc[n] = mfma(w.ah[6], bE, hacc[n]);
    hacc[n] = mfma(w.ah[7], bO, hacc[n]);
    hacc[n] = mfma(w.ah[8], dirB, hacc[n]);    // dirs + bias kstep
    outT[n] = make_float4(fmaxf(hacc[n][0], 0.f),
                          sigm(hacc[n][1]), sigm(hacc[n][2]), sigm(hacc[n][3]));
  }
}

__global__ __launch_bounds__(64, 1) void nerf_mfma(
    const float* __restrict__ rays_o, const float* __restrict__ rays_d,
    const float* __restrict__ rand_coarse, const float* __restrict__ u_fine,
    const float* __restrict__ W1, const float* __restrict__ b1,
    const float* __restrict__ W2, const float* __restrict__ b2,
    const float* __restrict__ Wsg, const float* __restrict__ bsg,
    const float* __restrict__ Wrg, const float* __restrict__ brg,
    float* __restrict__ out, int nrays)
{
  const int lane = threadIdx.x;

  __shared__ float    s_e[NC];        // coarse t
  __shared__ float    s_tf[NT];       // sorted fine t
  __shared__ float    s_cdf[NC + 1];
  __shared__ int      s_exc[NC + 1];  // exclusive bin prefix
  __shared__ unsigned s_cnt[NC + 1];  // histogram of searchsorted bins
  __shared__ float4   s_out[NT];

  Wfrag w;
  load_weights(w, lane, W1, b1, W2, b2, Wsg, bsg, Wrg, brg);

  for (int rr = 0; rr < RPB; ++rr) {
    const int b = blockIdx.x * RPB + rr;
    if (b >= nrays) break;
    __syncthreads();

    const float ox = rays_o[b * 3 + 0], oy = rays_o[b * 3 + 1], oz = rays_o[b * 3 + 2];
    const float dxx = rays_d[b * 3 + 0], dyy = rays_d[b * 3 + 1], dzz = rays_d[b * 3 + 2];
    const bf16x8 dirB = (lane < 32) ? mk4(pk2(dxx, dyy), pk2(dzz, 1.f), 0u, 0u)
                                    : mk4(0u, 0u, 0u, 0u);

    // ---------------- coarse stratified sampling ----------------
    const float step = (T_FAR - T_NEAR) / (float)(NC - 1);
    const float tl  = T_NEAR + step * (float)lane;
    const float tlp = T_NEAR + step * (float)(lane - 1);
    const float tln = T_NEAR + step * (float)(lane + 1);
    const float lower = (lane == 0)      ? tl : 0.5f * (tlp + tl);
    const float upper = (lane == NC - 1) ? tl : 0.5f * (tl + tln);
    const float t = lower + (upper - lower) * rand_coarse[b * NC + lane];

    // ---------------- coarse MLP (2 tiles, ILP-2) ----------------
    {
      float ts[2] = { __shfl(t, lane & 31), __shfl(t, 32 + (lane & 31)) };
      float4 oT[2];
      mlp_tileN<2>(w, ts, ox, oy, oz, dxx, dyy, dzz, dirB, lane, oT);
      if (lane < 32) {
        s_out[lane]      = oT[0];
        s_out[32 + lane] = oT[1];
      }
    }
    __syncthreads();
    float4 o4 = s_out[lane];
    float sig = o4.x, mr = o4.y, mg = o4.z, mb = o4.w;

    // ---------------- coarse volume rendering (DPP scans) ----------------
    float tnext = __shfl_down(t, 1);
    float delta = (lane == NC - 1) ? 1e10f : (tnext - t);
    float alpha = 1.0f - __expf(-sig * delta);
    float fac   = 1.0f - alpha + 1e-10f;

    float ip = dpp_scan_mul(fac);            // inclusive cumprod
    float T = __shfl_up(ip, 1);
    if (lane == 0) T = 1.0f;
    float wgt = T * alpha;

    float cr = dpp_scan_add(wgt * mr);       // lane 63 = total
    float cg = dpp_scan_add(wgt * mg);
    float cb = dpp_scan_add(wgt * mb);
    if (lane == 63) {
      out[b * 3 + 0] = cr; out[b * 3 + 1] = cg; out[b * 3 + 2] = cb;
    }

    s_e[lane] = t;
    s_cnt[lane] = 0u;
    if (lane == 0) s_cnt[NC] = 0u;

    // ---------------- importance sampling: cdf (scan + total from lane 63) --
    float wp = wgt + 1e-5f;
    float wsc = dpp_scan_add(wp);            // inclusive cumsum of wp
    float wsum = __shfl(wsc, 63);            // total (all lanes)
    float csum = wsc / wsum;                 // cdf[lane+1]
    if (lane == 0) s_cdf[0] = 0.0f;
    s_cdf[lane + 1] = csum;
    __syncthreads();

    // ---------------- searchsorted + histogram (2 u's per lane) ----------------
    int indh[2]; unsigned rh[2];
    #pragma unroll
    for (int h = 0; h < 2; ++h) {
      float u = u_fine[b * NF + h * 64 + lane];
      int ind = 0;
      #pragma unroll
      for (int j = 0; j < NC + 1; ++j)
        ind += (s_cdf[j] <= u) ? 1 : 0;     // side='right'; ind >= 1 (cdf[0]=0)
      if (ind > NC) ind = NC;               // value-equivalent clamp
      indh[h] = ind;
      rh[h] = atomicAdd(&s_cnt[ind], 1u);   // tie rank (equal values)
    }
    __syncthreads();

    // ---------------- analytic "sort": prefix over bins + scatter ----------------
    int c  = (int)s_cnt[lane];
    int ci = dpp_scan_addi(c);              // inclusive prefix of bin counts
    s_exc[lane] = ci - c;                   // excl prefix of bins 0..63
    if (lane == 63) s_exc[NC] = ci;         // excl prefix of bin 64
    s_tf[lane + ci] = t;                    // t_c[i] -> i + incl_prefix(i)
    __syncthreads();

    #pragma unroll
    for (int h = 0; h < 2; ++h) {
      int ind = indh[h];
      int below = ind - 1; if (below > NC - 1) below = NC - 1;
      int above = ind;     if (above > NC - 1) above = NC - 1;
      float tmid = 0.5f * (s_e[below] + s_e[above]);
      s_tf[ind + s_exc[ind] + (int)rh[h]] = tmid;
    }
    __syncthreads();

    // ---------------- fine MLP (6 tiles = 2 calls of ILP-3) ----------------
    #pragma unroll
    for (int p = 0; p < 2; ++p) {
      float ts[3] = { s_tf[(p * 3 + 0) * 32 + (lane & 31)],
                      s_tf[(p * 3 + 1) * 32 + (lane & 31)],
                      s_tf[(p * 3 + 2) * 32 + (lane & 31)] };
      float4 fT[3];
      mlp_tileN<3>(w, ts, ox, oy, oz, dxx, dyy, dzz, dirB, lane, fT);
      if (lane < 32) {
        #pragma unroll
        for (int n = 0; n < 3; ++n)
          s_out[(p * 3 + n) * 32 + lane] = fT[n];
      }
    }
    __syncthreads();

    // ---------------- fine render: 3 contiguous samples per lane ----------------
    float tq[3], rr2[3], gg[3], bb2[3], al[3], fc[3];
    #pragma unroll
    for (int q = 0; q < 3; ++q) {
      int sidx = 3 * lane + q;
      float tf_ = s_tf[sidx];
      float4 m4 = s_out[sidx];
      tq[q] = tf_; rr2[q] = m4.y; gg[q] = m4.z; bb2[q] = m4.w;
      float dlt = (sidx == NT - 1) ? 1e10f : (s_tf[sidx + 1] - tf_);
      al[q] = 1.0f - __expf(-m4.x * dlt);
      fc[q] = 1.0f - al[q] + 1e-10f;
    }

    float pl = fc[0] * fc[1] * fc[2];
    float ipf = dpp_scan_mul(pl);           // inclusive cumprod over lanes
    float P = __shfl_up(ipf, 1);
    if (lane == 0) P = 1.0f;

    float w0 = P * al[0];
    float w1 = P * fc[0] * al[1];
    float w2 = P * fc[0] * fc[1] * al[2];

    float cfr = dpp_scan_add(fmaf(w0, rr2[0], fmaf(w1, rr2[1], w2 * rr2[2])));
    float cfg = dpp_scan_add(fmaf(w0, gg[0],  fmaf(w1, gg[1],  w2 * gg[2])));
    float cfb = dpp_scan_add(fmaf(w0, bb2[0], fmaf(w1, bb2[1], w2 * bb2[2])));
    float dep = dpp_scan_add(fmaf(w0, tq[0],  fmaf(w1, tq[1],  w2 * tq[2])));

    if (lane == 63) {
      out[nrays * 3 + b * 3 + 0] = cfr;
      out[nrays * 3 + b * 3 + 1] = cfg;
      out[nrays * 3 + b * 3 + 2] = cfb;
      out[nrays * 6 + b]         = dep;
    }
  }
}

} // anonymous namespace

extern "C" void kernel_launch(void* const* d_in, const int* in_sizes, int n_in,
                              void* d_out, int out_size, void* d_ws, size_t ws_size,
                              hipStream_t stream) {
  const float* rays_o      = (const float*)d_in[0];
  const float* rays_d      = (const float*)d_in[1];
  const float* rand_coarse = (const float*)d_in[2];
  const float* u_fine      = (const float*)d_in[3];
  const float* W1   = (const float*)d_in[4];
  const float* b1   = (const float*)d_in[5];
  const float* W2   = (const float*)d_in[6];
  const float* b2   = (const float*)d_in[7];
  const float* Wsig = (const float*)d_in[8];
  const float* bsig = (const float*)d_in[9];
  const float* Wrgb = (const float*)d_in[10];
  const float* brgb = (const float*)d_in[11];
  float* out = (float*)d_out;

  const int nrays = in_sizes[0] / 3;
  const int grid  = (nrays + RPB - 1) / RPB;

  hipLaunchKernelGGL(nerf_mfma, dim3(grid), dim3(64), 0, stream,
                     rays_o, rays_d, rand_coarse, u_fine,
                     W1, b1, W2, b2, Wsig, bsig, Wrgb, brgb,
                     out, nrays);
}

// Round 18
// 120.840 us; speedup vs baseline: 1.1228x; 1.1228x over previous
//
#include <hip/hip_runtime.h>
#include <math.h>

namespace {

constexpr int NC  = 64;      // coarse samples
constexpr int NF  = 128;     // fine (importance) samples
constexpr int NT  = NC + NF; // 192 total fine-pass samples
constexpr int HID = 128;
constexpr float T_NEAR = 2.0f, T_FAR = 6.0f;
constexpr int RPB = 8;       // rays per block: grid=1024 -> 4 blk/CU -> 1 wave/SIMD

typedef __attribute__((ext_vector_type(8)))  short bf16x8;   // 8 bf16 = 4 VGPRs
typedef __attribute__((ext_vector_type(16))) float f32x16;   // MFMA 32x32 acc
typedef __attribute__((ext_vector_type(4)))  unsigned int u32x4;
typedef __attribute__((ext_vector_type(2)))  __bf16 vbf2;

__device__ __forceinline__ unsigned int pk2(float a, float b) {
  vbf2 t; t[0] = (__bf16)a; t[1] = (__bf16)b;   // v_cvt_pk_bf16_f32
  return __builtin_bit_cast(unsigned int, t);
}
__device__ __forceinline__ bf16x8 mk4(unsigned int w0, unsigned int w1,
                                      unsigned int w2, unsigned int w3) {
  u32x4 u = {w0, w1, w2, w3};
  return __builtin_bit_cast(bf16x8, u);
}
__device__ __forceinline__ f32x16 zero16() {
  f32x16 z;
  #pragma unroll
  for (int i = 0; i < 16; ++i) z[i] = 0.f;
  return z;
}
__device__ __forceinline__ f32x16 mfma(bf16x8 a, bf16x8 b, f32x16 c) {
  return __builtin_amdgcn_mfma_f32_32x32x16_bf16(a, b, c, 0, 0, 0);
}

// ---------- DPP wave scans (pure VALU) ----------
template<int CTRL, int RMASK>
__device__ __forceinline__ float dpp_fmul(float x) {
  int sh = __builtin_amdgcn_update_dpp(0x3f800000 /*1.0f*/,
                                       __builtin_bit_cast(int, x),
                                       CTRL, RMASK, 0xf, false);
  return x * __builtin_bit_cast(float, sh);
}
template<int CTRL, int RMASK>
__device__ __forceinline__ float dpp_fadd(float x) {
  int sh = __builtin_amdgcn_update_dpp(0 /*0.0f*/,
                                       __builtin_bit_cast(int, x),
                                       CTRL, RMASK, 0xf, false);
  return x + __builtin_bit_cast(float, sh);
}
template<int CTRL, int RMASK>
__device__ __forceinline__ int dpp_iadd(int x) {
  return x + __builtin_amdgcn_update_dpp(0, x, CTRL, RMASK, 0xf, false);
}
__device__ __forceinline__ float dpp_scan_mul(float x) {
  x = dpp_fmul<0x111, 0xf>(x);
  x = dpp_fmul<0x112, 0xf>(x);
  x = dpp_fmul<0x114, 0xf>(x);
  x = dpp_fmul<0x118, 0xf>(x);
  x = dpp_fmul<0x142, 0xa>(x);
  x = dpp_fmul<0x143, 0xc>(x);
  return x;
}
__device__ __forceinline__ float dpp_scan_add(float x) {
  x = dpp_fadd<0x111, 0xf>(x);
  x = dpp_fadd<0x112, 0xf>(x);
  x = dpp_fadd<0x114, 0xf>(x);
  x = dpp_fadd<0x118, 0xf>(x);
  x = dpp_fadd<0x142, 0xa>(x);
  x = dpp_fadd<0x143, 0xc>(x);
  return x;
}
__device__ __forceinline__ int dpp_scan_addi(int x) {
  x = dpp_iadd<0x111, 0xf>(x);
  x = dpp_iadd<0x112, 0xf>(x);
  x = dpp_iadd<0x114, 0xf>(x);
  x = dpp_iadd<0x118, 0xf>(x);
  x = dpp_iadd<0x142, 0xa>(x);
  x = dpp_iadd<0x143, 0xc>(x);
  return x;
}

// k-slot permutation (HW-verified round 4): slot (k9,hi,i) of the B operand
// holds, in-lane, C-tile register r of the producing layer.
__device__ __forceinline__ int kperm(int k9, int hi, int i) {
  return 32 * (k9 >> 1) + 16 * (k9 & 1) + 4 * hi + (i & 3) + 8 * (i >> 2);
}

// acc C-tile -> relu -> two B-fragment ksteps, pure in-lane VALU.
__device__ __forceinline__ void cvt_direct(const f32x16& a, bf16x8& bE, bf16x8& bO) {
  float v[16];
  #pragma unroll
  for (int r = 0; r < 16; ++r) v[r] = fmaxf(a[r], 0.f);
  bE = mk4(pk2(v[0],  v[1]),  pk2(v[2],  v[3]),
           pk2(v[4],  v[5]),  pk2(v[6],  v[7]));
  bO = mk4(pk2(v[8],  v[9]),  pk2(v[10], v[11]),
           pk2(v[12], v[13]), pk2(v[14], v[15]));
}

struct Wfrag {           // ALL weights resident in registers (~200 VGPRs)
  bf16x8 a1[4];          // W1ext^T [hid][k: x,y,z,b1]
  bf16x8 a2[4][9];       // W2ext^T, k<128 pi-permuted; k9=8: k=128 -> b2
  bf16x8 ah[9];          // head^T, k<128 pi-permuted; k9=8: dirs+bias
  bf16x8 bOne;           // B kstep8 of layer2: slot 128 -> 1.0
};

__device__ __forceinline__ void load_weights(Wfrag& w, int lane,
    const float* __restrict__ W1,  const float* __restrict__ b1,
    const float* __restrict__ W2,  const float* __restrict__ b2,
    const float* __restrict__ Wsg, const float* __restrict__ bsg,
    const float* __restrict__ Wrg, const float* __restrict__ brg) {
  const int hl = lane & 31;
  const int hi = lane >> 5;
  const bool lo = (lane < 32);

  #pragma unroll
  for (int m = 0; m < 4; ++m) {
    int h = 32 * m + hl;
    w.a1[m] = lo ? mk4(pk2(W1[h], W1[HID + h]), pk2(W1[2 * HID + h], b1[h]), 0u, 0u)
                 : mk4(0u, 0u, 0u, 0u);
  }
  #pragma unroll
  for (int m = 0; m < 4; ++m) {
    int h = 32 * m + hl;
    #pragma unroll
    for (int k9 = 0; k9 < 9; ++k9) {
      float e[8];
      #pragma unroll
      for (int i = 0; i < 8; ++i) {
        if (k9 < 8) e[i] = W2[kperm(k9, hi, i) * HID + h];
        else        e[i] = (8 * hi + i == 0) ? b2[h] : 0.f;
      }
      w.a2[m][k9] = mk4(pk2(e[0], e[1]), pk2(e[2], e[3]),
                        pk2(e[4], e[5]), pk2(e[6], e[7]));
    }
  }
  const int c = hl;
  #pragma unroll
  for (int k9 = 0; k9 < 9; ++k9) {
    float e[8];
    #pragma unroll
    for (int i = 0; i < 8; ++i) {
      int kk = (k9 < 8) ? kperm(k9, hi, i) : (128 + 8 * hi + i);
      float v = 0.f;
      if (c == 0)       { if (kk < 128) v = Wsg[kk]; else if (kk == 131) v = bsg[0]; }
      else if (c <= 3)  { if (kk < 131) v = Wrg[kk * 3 + (c - 1)]; else if (kk == 131) v = brg[c - 1]; }
      e[i] = v;
    }
    w.ah[k9] = mk4(pk2(e[0], e[1]), pk2(e[2], e[3]),
                   pk2(e[4], e[5]), pk2(e[6], e[7]));
  }
  w.bOne = lo ? mk4(pk2(1.f, 0.f), 0u, 0u, 0u) : mk4(0u, 0u, 0u, 0u);
}

__device__ __forceinline__ float sigm(float x) { return 1.f / (1.f + __expf(-x)); }

// N independent 32-sample tiles, acc-major schedule (round-16 verified) with
// PEELED first iteration: every accumulator chain starts as mfma(A,B,Z) where
// Z is a kernel-persistent zero f32x16 -> no per-call v_accvgpr_write
// zero-inits (~160 VALU insts saved per call). Summation order identical to
// rounds 4-16 (bitwise). Outputs valid in lanes 0-31.
template<int N>
__device__ __forceinline__ void mlp_tileN(const Wfrag& w, const f32x16& Z,
    const float* ts,
    float ox, float oy, float oz, float dxx, float dyy, float dzz,
    bf16x8 dirB, int lane, float4* outT) {
  const bool lo = (lane < 32);

  bf16x8 bP[N];
  #pragma unroll
  for (int n = 0; n < N; ++n) {
    float px = fmaf(dxx, ts[n], ox), py = fmaf(dyy, ts[n], oy), pz = fmaf(dzz, ts[n], oz);
    bP[n] = lo ? mk4(pk2(px, py), pk2(pz, 1.f), 0u, 0u) : mk4(0u, 0u, 0u, 0u);
  }

  f32x16 acc0[N], acc1[N], acc2[N], acc3[N];   // defined by first MFMA (C=Z)
  f32x16 hacc[N];

  // ---- m1 = 0 (peeled): chains begin from Z ----
  #pragma unroll
  for (int n = 0; n < N; ++n) {
    f32x16 l1 = mfma(w.a1[0], bP[n], Z);
    bf16x8 hE, hO;
    cvt_direct(l1, hE, hO);                    // bH ksteps {0, 1}
    acc0[n] = mfma(w.a2[0][0], hE, Z);
    acc0[n] = mfma(w.a2[0][1], hO, acc0[n]);
    acc1[n] = mfma(w.a2[1][0], hE, Z);
    acc1[n] = mfma(w.a2[1][1], hO, acc1[n]);
    acc2[n] = mfma(w.a2[2][0], hE, Z);
    acc2[n] = mfma(w.a2[2][1], hO, acc2[n]);
    acc3[n] = mfma(w.a2[3][0], hE, Z);
    acc3[n] = mfma(w.a2[3][1], hO, acc3[n]);
  }
  // ---- m1 = 1..3: accumulate ----
  #pragma unroll
  for (int m1 = 1; m1 < 4; ++m1) {
    #pragma unroll
    for (int n = 0; n < N; ++n) {
      f32x16 l1 = mfma(w.a1[m1], bP[n], Z);
      bf16x8 hE, hO;
      cvt_direct(l1, hE, hO);                  // bH ksteps {2m1, 2m1+1}
      acc0[n] = mfma(w.a2[0][2 * m1], hE, acc0[n]);
      acc0[n] = mfma(w.a2[0][2 * m1 + 1], hO, acc0[n]);
      acc1[n] = mfma(w.a2[1][2 * m1], hE, acc1[n]);
      acc1[n] = mfma(w.a2[1][2 * m1 + 1], hO, acc1[n]);
      acc2[n] = mfma(w.a2[2][2 * m1], hE, acc2[n]);
      acc2[n] = mfma(w.a2[2][2 * m1 + 1], hO, acc2[n]);
      acc3[n] = mfma(w.a2[3][2 * m1], hE, acc3[n]);
      acc3[n] = mfma(w.a2[3][2 * m1 + 1], hO, acc3[n]);
    }
  }
  // b2 bias kstep (same position in per-acc order as before)
  #pragma unroll
  for (int n = 0; n < N; ++n) {
    acc0[n] = mfma(w.a2[0][8], w.bOne, acc0[n]);
    acc1[n] = mfma(w.a2[1][8], w.bOne, acc1[n]);
    acc2[n] = mfma(w.a2[2][8], w.bOne, acc2[n]);
    acc3[n] = mfma(w.a2[3][8], w.bOne, acc3[n]);
  }
  // head: 4 cvt + 9 MFMA per tile; hacc chain begins from Z
  #pragma unroll
  for (int n = 0; n < N; ++n) {
    bf16x8 bE, bO;
    cvt_direct(acc0[n], bE, bO);
    hacc[n] = mfma(w.ah[0], bE, Z);
    hacc[n] = mfma(w.ah[1], bO, hacc[n]);
    cvt_direct(acc1[n], bE, bO);
    hacc[n] = mfma(w.ah[2], bE, hacc[n]);
    hacc[n] = mfma(w.ah[3], bO, hacc[n]);
    cvt_direct(acc2[n], bE, bO);
    hacc[n] = mfma(w.ah[4], bE, hacc[n]);
    hacc[n] = mfma(w.ah[5], bO, hacc[n]);
    cvt_direct(acc3[n], bE, bO);
    hacc[n] = mfma(w.ah[6], bE, hacc[n]);
    hacc[n] = mfma(w.ah[7], bO, hacc[n]);
    hacc[n] = mfma(w.ah[8], dirB, hacc[n]);    // dirs + bias kstep
    outT[n] = make_float4(fmaxf(hacc[n][0], 0.f),
                          sigm(hacc[n][1]), sigm(hacc[n][2]), sigm(hacc[n][3]));
  }
}

__global__ __launch_bounds__(64, 1) void nerf_mfma(
    const float* __restrict__ rays_o, const float* __restrict__ rays_d,
    const float* __restrict__ rand_coarse, const float* __restrict__ u_fine,
    const float* __restrict__ W1, const float* __restrict__ b1,
    const float* __restrict__ W2, const float* __restrict__ b2,
    const float* __restrict__ Wsg, const float* __restrict__ bsg,
    const float* __restrict__ Wrg, const float* __restrict__ brg,
    float* __restrict__ out, int nrays)
{
  const int lane = threadIdx.x;

  __shared__ float    s_e[NC];        // coarse t
  __shared__ float    s_tf[NT];       // sorted fine t
  __shared__ float    s_cdf[NC + 1];
  __shared__ int      s_exc[NC + 1];  // exclusive bin prefix
  __shared__ unsigned s_cnt[NC + 1];  // histogram of searchsorted bins
  __shared__ float4   s_out[NT];

  Wfrag w;
  load_weights(w, lane, W1, b1, W2, b2, Wsg, bsg, Wrg, brg);
  const f32x16 Z = zero16();          // persistent zero C-operand (16 regs)

  for (int rr = 0; rr < RPB; ++rr) {
    const int b = blockIdx.x * RPB + rr;
    if (b >= nrays) break;
    __syncthreads();

    const float ox = rays_o[b * 3 + 0], oy = rays_o[b * 3 + 1], oz = rays_o[b * 3 + 2];
    const float dxx = rays_d[b * 3 + 0], dyy = rays_d[b * 3 + 1], dzz = rays_d[b * 3 + 2];
    const bf16x8 dirB = (lane < 32) ? mk4(pk2(dxx, dyy), pk2(dzz, 1.f), 0u, 0u)
                                    : mk4(0u, 0u, 0u, 0u);

    // ---------------- coarse stratified sampling ----------------
    const float step = (T_FAR - T_NEAR) / (float)(NC - 1);
    const float tl  = T_NEAR + step * (float)lane;
    const float tlp = T_NEAR + step * (float)(lane - 1);
    const float tln = T_NEAR + step * (float)(lane + 1);
    const float lower = (lane == 0)      ? tl : 0.5f * (tlp + tl);
    const float upper = (lane == NC - 1) ? tl : 0.5f * (tl + tln);
    const float t = lower + (upper - lower) * rand_coarse[b * NC + lane];

    // ---------------- coarse MLP (2 tiles, ILP-2) ----------------
    {
      float ts[2] = { __shfl(t, lane & 31), __shfl(t, 32 + (lane & 31)) };
      float4 oT[2];
      mlp_tileN<2>(w, Z, ts, ox, oy, oz, dxx, dyy, dzz, dirB, lane, oT);
      if (lane < 32) {
        s_out[lane]      = oT[0];
        s_out[32 + lane] = oT[1];
      }
    }
    __syncthreads();
    float4 o4 = s_out[lane];
    float sig = o4.x, mr = o4.y, mg = o4.z, mb = o4.w;

    // ---------------- coarse volume rendering (DPP scans) ----------------
    float tnext = __shfl_down(t, 1);
    float delta = (lane == NC - 1) ? 1e10f : (tnext - t);
    float alpha = 1.0f - __expf(-sig * delta);
    float fac   = 1.0f - alpha + 1e-10f;

    float ip = dpp_scan_mul(fac);            // inclusive cumprod
    float T = __shfl_up(ip, 1);
    if (lane == 0) T = 1.0f;
    float wgt = T * alpha;

    float cr = dpp_scan_add(wgt * mr);       // lane 63 = total
    float cg = dpp_scan_add(wgt * mg);
    float cb = dpp_scan_add(wgt * mb);
    if (lane == 63) {
      out[b * 3 + 0] = cr; out[b * 3 + 1] = cg; out[b * 3 + 2] = cb;
    }

    s_e[lane] = t;
    s_cnt[lane] = 0u;
    if (lane == 0) s_cnt[NC] = 0u;

    // ---------------- importance sampling: cdf (scan + total from lane 63) --
    float wp = wgt + 1e-5f;
    float wsc = dpp_scan_add(wp);            // inclusive cumsum of wp
    float wsum = __shfl(wsc, 63);            // total (all lanes)
    float csum = wsc / wsum;                 // cdf[lane+1]
    if (lane == 0) s_cdf[0] = 0.0f;
    s_cdf[lane + 1] = csum;
    __syncthreads();

    // ---------------- searchsorted + histogram (2 u's per lane) ----------------
    int indh[2]; unsigned rh[2];
    #pragma unroll
    for (int h = 0; h < 2; ++h) {
      float u = u_fine[b * NF + h * 64 + lane];
      int ind = 0;
      #pragma unroll
      for (int j = 0; j < NC + 1; ++j)
        ind += (s_cdf[j] <= u) ? 1 : 0;     // side='right'; ind >= 1 (cdf[0]=0)
      if (ind > NC) ind = NC;               // value-equivalent clamp
      indh[h] = ind;
      rh[h] = atomicAdd(&s_cnt[ind], 1u);   // tie rank (equal values)
    }
    __syncthreads();

    // ---------------- analytic "sort": prefix over bins + scatter ----------------
    int c  = (int)s_cnt[lane];
    int ci = dpp_scan_addi(c);              // inclusive prefix of bin counts
    s_exc[lane] = ci - c;                   // excl prefix of bins 0..63
    if (lane == 63) s_exc[NC] = ci;         // excl prefix of bin 64
    s_tf[lane + ci] = t;                    // t_c[i] -> i + incl_prefix(i)
    __syncthreads();

    #pragma unroll
    for (int h = 0; h < 2; ++h) {
      int ind = indh[h];
      int below = ind - 1; if (below > NC - 1) below = NC - 1;
      int above = ind;     if (above > NC - 1) above = NC - 1;
      float tmid = 0.5f * (s_e[below] + s_e[above]);
      s_tf[ind + s_exc[ind] + (int)rh[h]] = tmid;
    }
    __syncthreads();

    // ---------------- fine MLP (6 tiles = 3 calls of ILP-2) ----------------
    #pragma unroll
    for (int p = 0; p < 3; ++p) {
      float ts[2] = { s_tf[(p * 2 + 0) * 32 + (lane & 31)],
                      s_tf[(p * 2 + 1) * 32 + (lane & 31)] };
      float4 fT[2];
      mlp_tileN<2>(w, Z, ts, ox, oy, oz, dxx, dyy, dzz, dirB, lane, fT);
      if (lane < 32) {
        s_out[(p * 2 + 0) * 32 + lane] = fT[0];
        s_out[(p * 2 + 1) * 32 + lane] = fT[1];
      }
    }
    __syncthreads();

    // ---------------- fine render: 3 contiguous samples per lane ----------------
    float tq[3], rr2[3], gg[3], bb2[3], al[3], fc[3];
    #pragma unroll
    for (int q = 0; q < 3; ++q) {
      int sidx = 3 * lane + q;
      float tf_ = s_tf[sidx];
      float4 m4 = s_out[sidx];
      tq[q] = tf_; rr2[q] = m4.y; gg[q] = m4.z; bb2[q] = m4.w;
      float dlt = (sidx == NT - 1) ? 1e10f : (s_tf[sidx + 1] - tf_);
      al[q] = 1.0f - __expf(-m4.x * dlt);
      fc[q] = 1.0f - al[q] + 1e-10f;
    }

    float pl = fc[0] * fc[1] * fc[2];
    float ipf = dpp_scan_mul(pl);           // inclusive cumprod over lanes
    float P = __shfl_up(ipf, 1);
    if (lane == 0) P = 1.0f;

    float w0 = P * al[0];
    float w1 = P * fc[0] * al[1];
    float w2 = P * fc[0] * fc[1] * al[2];

    float cfr = dpp_scan_add(fmaf(w0, rr2[0], fmaf(w1, rr2[1], w2 * rr2[2])));
    float cfg = dpp_scan_add(fmaf(w0, gg[0],  fmaf(w1, gg[1],  w2 * gg[2])));
    float cfb = dpp_scan_add(fmaf(w0, bb2[0], fmaf(w1, bb2[1], w2 * bb2[2])));
    float dep = dpp_scan_add(fmaf(w0, tq[0],  fmaf(w1, tq[1],  w2 * tq[2])));

    if (lane == 63) {
      out[nrays * 3 + b * 3 + 0] = cfr;
      out[nrays * 3 + b * 3 + 1] = cfg;
      out[nrays * 3 + b * 3 + 2] = cfb;
      out[nrays * 6 + b]         = dep;
    }
  }
}

} // anonymous namespace

extern "C" void kernel_launch(void* const* d_in, const int* in_sizes, int n_in,
                              void* d_out, int out_size, void* d_ws, size_t ws_size,
                              hipStream_t stream) {
  const float* rays_o      = (const float*)d_in[0];
  const float* rays_d      = (const float*)d_in[1];
  const float* rand_coarse = (const float*)d_in[2];
  const float* u_fine      = (const float*)d_in[3];
  const float* W1   = (const float*)d_in[4];
  const float* b1   = (const float*)d_in[5];
  const float* W2   = (const float*)d_in[6];
  const float* b2   = (const float*)d_in[7];
  const float* Wsig = (const float*)d_in[8];
  const float* bsig = (const float*)d_in[9];
  const float* Wrgb = (const float*)d_in[10];
  const float* brgb = (const float*)d_in[11];
  float* out = (float*)d_out;

  const int nrays = in_sizes[0] / 3;
  const int grid  = (nrays + RPB - 1) / RPB;

  hipLaunchKernelGGL(nerf_mfma, dim3(grid), dim3(64), 0, stream,
                     rays_o, rays_d, rand_coarse, u_fine,
                     W1, b1, W2, b2, Wsig, bsig, Wrgb, brgb,
                     out, nrays);
}

// Round 19
// 109.482 us; speedup vs baseline: 1.2393x; 1.1037x over previous
//
#include <hip/hip_runtime.h>
#include <math.h>

namespace {

constexpr int NC  = 64;      // coarse samples
constexpr int NF  = 128;     // fine (importance) samples
constexpr int NT  = NC + NF; // 192 total fine-pass samples
constexpr int HID = 128;
constexpr float T_NEAR = 2.0f, T_FAR = 6.0f;
constexpr int RPB = 8;       // rays per block: grid=1024 -> 4 blk/CU -> 1 wave/SIMD

typedef __attribute__((ext_vector_type(8)))  short bf16x8;   // 8 bf16 = 4 VGPRs
typedef __attribute__((ext_vector_type(16))) float f32x16;   // MFMA 32x32 acc
typedef __attribute__((ext_vector_type(4)))  unsigned int u32x4;
typedef __attribute__((ext_vector_type(2)))  __bf16 vbf2;

__device__ __forceinline__ unsigned int pk2(float a, float b) {
  vbf2 t; t[0] = (__bf16)a; t[1] = (__bf16)b;   // v_cvt_pk_bf16_f32
  return __builtin_bit_cast(unsigned int, t);
}
__device__ __forceinline__ bf16x8 mk4(unsigned int w0, unsigned int w1,
                                      unsigned int w2, unsigned int w3) {
  u32x4 u = {w0, w1, w2, w3};
  return __builtin_bit_cast(bf16x8, u);
}
__device__ __forceinline__ f32x16 zero16() {
  f32x16 z;
  #pragma unroll
  for (int i = 0; i < 16; ++i) z[i] = 0.f;
  return z;
}
__device__ __forceinline__ f32x16 mfma(bf16x8 a, bf16x8 b, f32x16 c) {
  return __builtin_amdgcn_mfma_f32_32x32x16_bf16(a, b, c, 0, 0, 0);
}

// Single-wave block: LDS ordering needs only an lgkm drain + compiler fence.
__device__ __forceinline__ void wave_fence() {
  asm volatile("s_waitcnt lgkmcnt(0)" ::: "memory");
}

// ---------- DPP wave scans (pure VALU) ----------
template<int CTRL, int RMASK>
__device__ __forceinline__ float dpp_fmul(float x) {
  int sh = __builtin_amdgcn_update_dpp(0x3f800000 /*1.0f*/,
                                       __builtin_bit_cast(int, x),
                                       CTRL, RMASK, 0xf, false);
  return x * __builtin_bit_cast(float, sh);
}
template<int CTRL, int RMASK>
__device__ __forceinline__ float dpp_fadd(float x) {
  int sh = __builtin_amdgcn_update_dpp(0 /*0.0f*/,
                                       __builtin_bit_cast(int, x),
                                       CTRL, RMASK, 0xf, false);
  return x + __builtin_bit_cast(float, sh);
}
template<int CTRL, int RMASK>
__device__ __forceinline__ int dpp_iadd(int x) {
  return x + __builtin_amdgcn_update_dpp(0, x, CTRL, RMASK, 0xf, false);
}
__device__ __forceinline__ float dpp_scan_mul(float x) {
  x = dpp_fmul<0x111, 0xf>(x);
  x = dpp_fmul<0x112, 0xf>(x);
  x = dpp_fmul<0x114, 0xf>(x);
  x = dpp_fmul<0x118, 0xf>(x);
  x = dpp_fmul<0x142, 0xa>(x);
  x = dpp_fmul<0x143, 0xc>(x);
  return x;
}
__device__ __forceinline__ float dpp_scan_add(float x) {
  x = dpp_fadd<0x111, 0xf>(x);
  x = dpp_fadd<0x112, 0xf>(x);
  x = dpp_fadd<0x114, 0xf>(x);
  x = dpp_fadd<0x118, 0xf>(x);
  x = dpp_fadd<0x142, 0xa>(x);
  x = dpp_fadd<0x143, 0xc>(x);
  return x;
}
__device__ __forceinline__ int dpp_scan_addi(int x) {
  x = dpp_iadd<0x111, 0xf>(x);
  x = dpp_iadd<0x112, 0xf>(x);
  x = dpp_iadd<0x114, 0xf>(x);
  x = dpp_iadd<0x118, 0xf>(x);
  x = dpp_iadd<0x142, 0xa>(x);
  x = dpp_iadd<0x143, 0xc>(x);
  return x;
}

// k-slot permutation (HW-verified round 4): slot (k9,hi,i) of the B operand
// holds, in-lane, C-tile register r of the producing layer.
__device__ __forceinline__ int kperm(int k9, int hi, int i) {
  return 32 * (k9 >> 1) + 16 * (k9 & 1) + 4 * hi + (i & 3) + 8 * (i >> 2);
}

// acc C-tile -> relu -> two B-fragment ksteps, pure in-lane VALU.
__device__ __forceinline__ void cvt_direct(const f32x16& a, bf16x8& bE, bf16x8& bO) {
  float v[16];
  #pragma unroll
  for (int r = 0; r < 16; ++r) v[r] = fmaxf(a[r], 0.f);
  bE = mk4(pk2(v[0],  v[1]),  pk2(v[2],  v[3]),
           pk2(v[4],  v[5]),  pk2(v[6],  v[7]));
  bO = mk4(pk2(v[8],  v[9]),  pk2(v[10], v[11]),
           pk2(v[12], v[13]), pk2(v[14], v[15]));
}

struct Wfrag {           // ALL weights resident in registers (~200 VGPRs)
  bf16x8 a1[4];          // W1ext^T [hid][k: x,y,z,b1]
  bf16x8 a2[4][9];       // W2ext^T, k<128 pi-permuted; k9=8: k=128 -> b2
  bf16x8 ah[9];          // head^T, k<128 pi-permuted; k9=8: dirs+bias
  bf16x8 bOne;           // B kstep8 of layer2: slot 128 -> 1.0
};

__device__ __forceinline__ void load_weights(Wfrag& w, int lane,
    const float* __restrict__ W1,  const float* __restrict__ b1,
    const float* __restrict__ W2,  const float* __restrict__ b2,
    const float* __restrict__ Wsg, const float* __restrict__ bsg,
    const float* __restrict__ Wrg, const float* __restrict__ brg) {
  const int hl = lane & 31;
  const int hi = lane >> 5;
  const bool lo = (lane < 32);

  #pragma unroll
  for (int m = 0; m < 4; ++m) {
    int h = 32 * m + hl;
    w.a1[m] = lo ? mk4(pk2(W1[h], W1[HID + h]), pk2(W1[2 * HID + h], b1[h]), 0u, 0u)
                 : mk4(0u, 0u, 0u, 0u);
  }
  #pragma unroll
  for (int m = 0; m < 4; ++m) {
    int h = 32 * m + hl;
    #pragma unroll
    for (int k9 = 0; k9 < 9; ++k9) {
      float e[8];
      #pragma unroll
      for (int i = 0; i < 8; ++i) {
        if (k9 < 8) e[i] = W2[kperm(k9, hi, i) * HID + h];
        else        e[i] = (8 * hi + i == 0) ? b2[h] : 0.f;
      }
      w.a2[m][k9] = mk4(pk2(e[0], e[1]), pk2(e[2], e[3]),
                        pk2(e[4], e[5]), pk2(e[6], e[7]));
    }
  }
  const int c = hl;
  #pragma unroll
  for (int k9 = 0; k9 < 9; ++k9) {
    float e[8];
    #pragma unroll
    for (int i = 0; i < 8; ++i) {
      int kk = (k9 < 8) ? kperm(k9, hi, i) : (128 + 8 * hi + i);
      float v = 0.f;
      if (c == 0)       { if (kk < 128) v = Wsg[kk]; else if (kk == 131) v = bsg[0]; }
      else if (c <= 3)  { if (kk < 131) v = Wrg[kk * 3 + (c - 1)]; else if (kk == 131) v = brg[c - 1]; }
      e[i] = v;
    }
    w.ah[k9] = mk4(pk2(e[0], e[1]), pk2(e[2], e[3]),
                   pk2(e[4], e[5]), pk2(e[6], e[7]));
  }
  w.bOne = lo ? mk4(pk2(1.f, 0.f), 0u, 0u, 0u) : mk4(0u, 0u, 0u, 0u);
}

__device__ __forceinline__ float sigm(float x) { return 1.f / (1.f + __expf(-x)); }

// N independent 32-sample tiles, acc-major schedule (round-16/18 verified)
// with peeled first iteration (chains start from persistent Z). Summation
// order identical to rounds 4-18 (bitwise). Outputs valid in lanes 0-31.
template<int N>
__device__ __forceinline__ void mlp_tileN(const Wfrag& w, const f32x16& Z,
    const float* ts,
    float ox, float oy, float oz, float dxx, float dyy, float dzz,
    bf16x8 dirB, int lane, float4* outT) {
  const bool lo = (lane < 32);

  bf16x8 bP[N];
  #pragma unroll
  for (int n = 0; n < N; ++n) {
    float px = fmaf(dxx, ts[n], ox), py = fmaf(dyy, ts[n], oy), pz = fmaf(dzz, ts[n], oz);
    bP[n] = lo ? mk4(pk2(px, py), pk2(pz, 1.f), 0u, 0u) : mk4(0u, 0u, 0u, 0u);
  }

  f32x16 acc0[N], acc1[N], acc2[N], acc3[N];   // defined by first MFMA (C=Z)
  f32x16 hacc[N];

  // ---- m1 = 0 (peeled): chains begin from Z ----
  #pragma unroll
  for (int n = 0; n < N; ++n) {
    f32x16 l1 = mfma(w.a1[0], bP[n], Z);
    bf16x8 hE, hO;
    cvt_direct(l1, hE, hO);                    // bH ksteps {0, 1}
    acc0[n] = mfma(w.a2[0][0], hE, Z);
    acc0[n] = mfma(w.a2[0][1], hO, acc0[n]);
    acc1[n] = mfma(w.a2[1][0], hE, Z);
    acc1[n] = mfma(w.a2[1][1], hO, acc1[n]);
    acc2[n] = mfma(w.a2[2][0], hE, Z);
    acc2[n] = mfma(w.a2[2][1], hO, acc2[n]);
    acc3[n] = mfma(w.a2[3][0], hE, Z);
    acc3[n] = mfma(w.a2[3][1], hO, acc3[n]);
  }
  // ---- m1 = 1..3: accumulate ----
  #pragma unroll
  for (int m1 = 1; m1 < 4; ++m1) {
    #pragma unroll
    for (int n = 0; n < N; ++n) {
      f32x16 l1 = mfma(w.a1[m1], bP[n], Z);
      bf16x8 hE, hO;
      cvt_direct(l1, hE, hO);                  // bH ksteps {2m1, 2m1+1}
      acc0[n] = mfma(w.a2[0][2 * m1], hE, acc0[n]);
      acc0[n] = mfma(w.a2[0][2 * m1 + 1], hO, acc0[n]);
      acc1[n] = mfma(w.a2[1][2 * m1], hE, acc1[n]);
      acc1[n] = mfma(w.a2[1][2 * m1 + 1], hO, acc1[n]);
      acc2[n] = mfma(w.a2[2][2 * m1], hE, acc2[n]);
      acc2[n] = mfma(w.a2[2][2 * m1 + 1], hO, acc2[n]);
      acc3[n] = mfma(w.a2[3][2 * m1], hE, acc3[n]);
      acc3[n] = mfma(w.a2[3][2 * m1 + 1], hO, acc3[n]);
    }
  }
  // b2 bias kstep (same position in per-acc order as before)
  #pragma unroll
  for (int n = 0; n < N; ++n) {
    acc0[n] = mfma(w.a2[0][8], w.bOne, acc0[n]);
    acc1[n] = mfma(w.a2[1][8], w.bOne, acc1[n]);
    acc2[n] = mfma(w.a2[2][8], w.bOne, acc2[n]);
    acc3[n] = mfma(w.a2[3][8], w.bOne, acc3[n]);
  }
  // head: 4 cvt + 9 MFMA per tile; hacc chain begins from Z
  #pragma unroll
  for (int n = 0; n < N; ++n) {
    bf16x8 bE, bO;
    cvt_direct(acc0[n], bE, bO);
    hacc[n] = mfma(w.ah[0], bE, Z);
    hacc[n] = mfma(w.ah[1], bO, hacc[n]);
    cvt_direct(acc1[n], bE, bO);
    hacc[n] = mfma(w.ah[2], bE, hacc[n]);
    hacc[n] = mfma(w.ah[3], bO, hacc[n]);
    cvt_direct(acc2[n], bE, bO);
    hacc[n] = mfma(w.ah[4], bE, hacc[n]);
    hacc[n] = mfma(w.ah[5], bO, hacc[n]);
    cvt_direct(acc3[n], bE, bO);
    hacc[n] = mfma(w.ah[6], bE, hacc[n]);
    hacc[n] = mfma(w.ah[7], bO, hacc[n]);
    hacc[n] = mfma(w.ah[8], dirB, hacc[n]);    // dirs + bias kstep
    outT[n] = make_float4(fmaxf(hacc[n][0], 0.f),
                          sigm(hacc[n][1]), sigm(hacc[n][2]), sigm(hacc[n][3]));
  }
}

__global__ __launch_bounds__(64, 1) void nerf_mfma(
    const float* __restrict__ rays_o, const float* __restrict__ rays_d,
    const float* __restrict__ rand_coarse, const float* __restrict__ u_fine,
    const float* __restrict__ W1, const float* __restrict__ b1,
    const float* __restrict__ W2, const float* __restrict__ b2,
    const float* __restrict__ Wsg, const float* __restrict__ bsg,
    const float* __restrict__ Wrg, const float* __restrict__ brg,
    float* __restrict__ out, int nrays)
{
  const int lane = threadIdx.x;

  __shared__ float    s_e[NC];        // coarse t
  __shared__ float    s_tf[NT];       // sorted fine t
  __shared__ float    s_cdf[NC + 1];
  __shared__ int      s_exc[NC + 1];  // exclusive bin prefix
  __shared__ unsigned s_cnt[NC + 1];  // histogram of searchsorted bins
  __shared__ float4   s_out[NT];

  Wfrag w;
  load_weights(w, lane, W1, b1, W2, b2, Wsg, bsg, Wrg, brg);
  const f32x16 Z = zero16();          // persistent zero C-operand (16 regs)

  for (int rr = 0; rr < RPB; ++rr) {
    const int b = blockIdx.x * RPB + rr;
    if (b >= nrays) break;
    wave_fence();                     // LDS reuse guard (single-wave block)

    const float ox = rays_o[b * 3 + 0], oy = rays_o[b * 3 + 1], oz = rays_o[b * 3 + 2];
    const float dxx = rays_d[b * 3 + 0], dyy = rays_d[b * 3 + 1], dzz = rays_d[b * 3 + 2];
    const bf16x8 dirB = (lane < 32) ? mk4(pk2(dxx, dyy), pk2(dzz, 1.f), 0u, 0u)
                                    : mk4(0u, 0u, 0u, 0u);

    // ---------------- coarse stratified sampling ----------------
    const float step = (T_FAR - T_NEAR) / (float)(NC - 1);
    const float tl  = T_NEAR + step * (float)lane;
    const float tlp = T_NEAR + step * (float)(lane - 1);
    const float tln = T_NEAR + step * (float)(lane + 1);
    const float lower = (lane == 0)      ? tl : 0.5f * (tlp + tl);
    const float upper = (lane == NC - 1) ? tl : 0.5f * (tl + tln);
    const float t = lower + (upper - lower) * rand_coarse[b * NC + lane];

    // ---------------- coarse MLP (2 tiles, ILP-2) ----------------
    {
      float ts[2] = { __shfl(t, lane & 31), __shfl(t, 32 + (lane & 31)) };
      float4 oT[2];
      mlp_tileN<2>(w, Z, ts, ox, oy, oz, dxx, dyy, dzz, dirB, lane, oT);
      if (lane < 32) {
        s_out[lane]      = oT[0];
        s_out[32 + lane] = oT[1];
      }
    }
    wave_fence();
    float4 o4 = s_out[lane];
    float sig = o4.x, mr = o4.y, mg = o4.z, mb = o4.w;

    // ---------------- coarse volume rendering (DPP scans) ----------------
    float tnext = __shfl_down(t, 1);
    float delta = (lane == NC - 1) ? 1e10f : (tnext - t);
    float alpha = 1.0f - __expf(-sig * delta);
    float fac   = 1.0f - alpha + 1e-10f;

    float ip = dpp_scan_mul(fac);            // inclusive cumprod
    float T = __shfl_up(ip, 1);
    if (lane == 0) T = 1.0f;
    float wgt = T * alpha;

    float cr = dpp_scan_add(wgt * mr);       // lane 63 = total
    float cg = dpp_scan_add(wgt * mg);
    float cb = dpp_scan_add(wgt * mb);
    if (lane == 63) {
      out[b * 3 + 0] = cr; out[b * 3 + 1] = cg; out[b * 3 + 2] = cb;
    }

    s_e[lane] = t;
    s_cnt[lane] = 0u;
    if (lane == 0) s_cnt[NC] = 0u;

    // ---------------- importance sampling: cdf (scan + total from lane 63) --
    float wp = wgt + 1e-5f;
    float wsc = dpp_scan_add(wp);            // inclusive cumsum of wp
    float wsum = __shfl(wsc, 63);            // total (all lanes)
    float csum = wsc / wsum;                 // cdf[lane+1]; lane63 -> exactly 1.0
    if (lane == 0) s_cdf[0] = 0.0f;
    s_cdf[lane + 1] = csum;
    wave_fence();

    // ---------------- searchsorted (monotone bisection) + histogram ---------
    // cdf strictly increasing; cdf[0]=0 <= u always; cdf[64]=1.0 > u always
    // (u in [0,1)). ind = 1 + max{j<=63 : cdf[j] <= u}  == linear count.
    int indh[2]; unsigned rh[2];
    #pragma unroll
    for (int h = 0; h < 2; ++h) {
      float u = u_fine[b * NF + h * 64 + lane];
      int pos = 0;
      #pragma unroll
      for (int s = 32; s; s >>= 1) {         // 6 steps; cand <= 63 always
        int cand = pos + s;
        pos = (s_cdf[cand] <= u) ? cand : pos;
      }
      int ind = pos + 1;                     // in [1, 64]
      indh[h] = ind;
      rh[h] = atomicAdd(&s_cnt[ind], 1u);    // tie rank (equal values)
    }
    wave_fence();

    // ---------------- analytic "sort": prefix over bins + scatter ----------------
    int c  = (int)s_cnt[lane];
    int ci = dpp_scan_addi(c);              // inclusive prefix of bin counts
    s_exc[lane] = ci - c;                   // excl prefix of bins 0..63
    if (lane == 63) s_exc[NC] = ci;         // excl prefix of bin 64
    s_tf[lane + ci] = t;                    // t_c[i] -> i + incl_prefix(i)
    wave_fence();

    #pragma unroll
    for (int h = 0; h < 2; ++h) {
      int ind = indh[h];
      int below = ind - 1; if (below > NC - 1) below = NC - 1;
      int above = ind;     if (above > NC - 1) above = NC - 1;
      float tmid = 0.5f * (s_e[below] + s_e[above]);
      s_tf[ind + s_exc[ind] + (int)rh[h]] = tmid;
    }
    wave_fence();

    // ---------------- fine MLP (6 tiles = 3 calls of ILP-2) ----------------
    #pragma unroll
    for (int p = 0; p < 3; ++p) {
      float ts[2] = { s_tf[(p * 2 + 0) * 32 + (lane & 31)],
                      s_tf[(p * 2 + 1) * 32 + (lane & 31)] };
      float4 fT[2];
      mlp_tileN<2>(w, Z, ts, ox, oy, oz, dxx, dyy, dzz, dirB, lane, fT);
      if (lane < 32) {
        s_out[(p * 2 + 0) * 32 + lane] = fT[0];
        s_out[(p * 2 + 1) * 32 + lane] = fT[1];
      }
    }
    wave_fence();

    // ---------------- fine render: 3 contiguous samples per lane ----------------
    float tq[3], rr2[3], gg[3], bb2[3], al[3], fc[3];
    #pragma unroll
    for (int q = 0; q < 3; ++q) {
      int sidx = 3 * lane + q;
      float tf_ = s_tf[sidx];
      float4 m4 = s_out[sidx];
      tq[q] = tf_; rr2[q] = m4.y; gg[q] = m4.z; bb2[q] = m4.w;
      float dlt = (sidx == NT - 1) ? 1e10f : (s_tf[sidx + 1] - tf_);
      al[q] = 1.0f - __expf(-m4.x * dlt);
      fc[q] = 1.0f - al[q] + 1e-10f;
    }

    float pl = fc[0] * fc[1] * fc[2];
    float ipf = dpp_scan_mul(pl);           // inclusive cumprod over lanes
    float P = __shfl_up(ipf, 1);
    if (lane == 0) P = 1.0f;

    float w0 = P * al[0];
    float w1 = P * fc[0] * al[1];
    float w2 = P * fc[0] * fc[1] * al[2];

    float cfr = dpp_scan_add(fmaf(w0, rr2[0], fmaf(w1, rr2[1], w2 * rr2[2])));
    float cfg = dpp_scan_add(fmaf(w0, gg[0],  fmaf(w1, gg[1],  w2 * gg[2])));
    float cfb = dpp_scan_add(fmaf(w0, bb2[0], fmaf(w1, bb2[1], w2 * bb2[2])));
    float dep = dpp_scan_add(fmaf(w0, tq[0],  fmaf(w1, tq[1],  w2 * tq[2])));

    if (lane == 63) {
      out[nrays * 3 + b * 3 + 0] = cfr;
      out[nrays * 3 + b * 3 + 1] = cfg;
      out[nrays * 3 + b * 3 + 2] = cfb;
      out[nrays * 6 + b]         = dep;
    }
  }
}

} // anonymous namespace

extern "C" void kernel_launch(void* const* d_in, const int* in_sizes, int n_in,
                              void* d_out, int out_size, void* d_ws, size_t ws_size,
                              hipStream_t stream) {
  const float* rays_o      = (const float*)d_in[0];
  const float* rays_d      = (const float*)d_in[1];
  const float* rand_coarse = (const float*)d_in[2];
  const float* u_fine      = (const float*)d_in[3];
  const float* W1   = (const float*)d_in[4];
  const float* b1   = (const float*)d_in[5];
  const float* W2   = (const float*)d_in[6];
  const float* b2   = (const float*)d_in[7];
  const float* Wsig = (const float*)d_in[8];
  const float* bsig = (const float*)d_in[9];
  const float* Wrgb = (const float*)d_in[10];
  const float* brgb = (const float*)d_in[11];
  float* out = (float*)d_out;

  const int nrays = in_sizes[0] / 3;
  const int grid  = (nrays + RPB - 1) / RPB;

  hipLaunchKernelGGL(nerf_mfma, dim3(grid), dim3(64), 0, stream,
                     rays_o, rays_d, rand_coarse, u_fine,
                     W1, b1, W2, b2, Wsig, bsig, Wrgb, brgb,
                     out, nrays);
}